// Round 9
// baseline (283.247 us; speedup 1.0000x reference)
//
#include <hip/hip_runtime.h>

namespace {
constexpr int S_LEN = 512;
constexpr int BATCH = 1024;
constexpr int TAG = 64;
constexpr int START_IDX = 0;
constexpr int END_IDX = 1;
constexpr int CHUNK = 64;              // steps per LDS feat chunk (16 KB)
constexpr float LN2F = 0.69314718055994530942f;

typedef float v4f __attribute__((ext_vector_type(4)));

typedef const __attribute__((address_space(1))) void* gas_ptr;
typedef __attribute__((address_space(3))) void* las_ptr;

__device__ inline void gld_lds16(const float* g, float* l) {
  // LDS dest = wave-uniform base + lane*16 (hardware); global src is per-lane.
  __builtin_amdgcn_global_load_lds((gas_ptr)(const void*)g, (las_ptr)(void*)l, 16, 0, 0);
}

template <int CTRL>
__device__ __forceinline__ unsigned dppmov(unsigned v) {
  return (unsigned)__builtin_amdgcn_mov_dpp((int)v, CTRL, 0xF, 0xF, false);
}

__device__ __forceinline__ unsigned swz_x16(unsigned v) {
  // ds_swizzle BitMode: xor_mask=16, and_mask=0x1F -> lane ^ 16 (HW-validated R6)
  return (unsigned)__builtin_amdgcn_ds_swizzle((int)v, 0x401F);
}

// Fill u[1..15] from root u[0] via DPP (HW-validated in round 6, absmax 0.0).
__device__ __forceinline__ void subtree16(unsigned* u) {
  u[8]  = dppmov<0x128>(u[0]);   // row_ror:8
  u[4]  = dppmov<0x124>(u[0]);   // row_ror:4
  u[12] = dppmov<0x124>(u[8]);
  u[2]  = dppmov<0x4E>(u[0]);    // quad_perm xor2
  u[6]  = dppmov<0x4E>(u[4]);
  u[10] = dppmov<0x4E>(u[8]);
  u[14] = dppmov<0x4E>(u[12]);
  u[1]  = dppmov<0xB1>(u[0]);    // quad_perm xor1
  u[3]  = dppmov<0xB1>(u[2]);
  u[5]  = dppmov<0xB1>(u[4]);
  u[7]  = dppmov<0xB1>(u[6]);
  u[9]  = dppmov<0xB1>(u[8]);
  u[11] = dppmov<0xB1>(u[10]);
  u[13] = dppmov<0xB1>(u[12]);
  u[15] = dppmov<0xB1>(u[14]);
}
}

// One wave (64 lanes) per batch; lane = destination tag j.
// Linear-domain recurrence: p_j = exp(alpha_j - etot*ln2), exact power-of-2 renorm
// from exponent bits of lane 2's p.
//   t_j = sum_r p[g_r] * E[j, g_r]   (in-register all-gather; slot->lane mapping
//                                     captured by index simulation, E pre-permuted)
// vs round 6 (correct, 707 cy/step): the three DS root ops are now INDEPENDENT
// functions of u[0] alone (swizzle^16, bpermute^32, bpermute^48 with loop-invariant
// address VGPRs) and issue back-to-back; their latency hides under subtree A
// (15 DPP + 16 FMA on u[0]'s coset, no DS dependence). R6's two SERIAL DS ops at
// the root were the measured ~240-300 cy stall. Only R6-validated primitives used
// (R8's permlane asm broke coverage — inline-asm semantics gamble, never again).
__global__ __launch_bounds__(64, 1) void crf_fwd_kernel(
    const float* __restrict__ feats,   // [S, B, T]
    const float* __restrict__ mask,    // [S, B]
    const float* __restrict__ trans,   // [T, T]
    float* __restrict__ out) {         // [B]
  const int b = blockIdx.x;
  const int lane = threadIdx.x;  // tag j

  __shared__ __align__(16) float fchunk[2][CHUNK * TAG];  // 2 x 16 KB

  // ---- effective length L = sum_s mask[s,b] (mask monotone non-increasing) ----
  int L;
  {
    float sum = 0.0f;
#pragma unroll
    for (int k = 0; k < S_LEN / 64; ++k) sum += mask[(size_t)(lane + 64 * k) * BATCH + b];
#pragma unroll
    for (int off = 32; off >= 1; off >>= 1) sum += __shfl_xor(sum, off, 64);
    L = (int)(sum + 0.5f);
  }

  // loop-invariant bpermute byte-addresses for the ^32 and ^48 roots
  const int addr32 = (lane ^ 32) << 2;
  const int addr48 = (lane ^ 48) << 2;

  // ---- index simulation: run the identical network on the lane index itself ----
  float Eg[64];
  {
    unsigned gi[64];
    gi[0]  = (unsigned)lane;
    gi[16] = swz_x16(gi[0]);
    gi[32] = (unsigned)__builtin_amdgcn_ds_bpermute(addr32, (int)gi[0]);
    gi[48] = (unsigned)__builtin_amdgcn_ds_bpermute(addr48, (int)gi[0]);
    subtree16(gi);
    subtree16(gi + 16);
    subtree16(gi + 32);
    subtree16(gi + 48);
    const float* trow = trans + lane * TAG;
#pragma unroll
    for (int r = 0; r < 64; ++r) Eg[r] = __expf(trow[gi[r]]);  // exp(-1e4) -> 0
  }

  // per-lane invariant staging address: one gld_lds16 moves 4 rows (4 x 256 B)
  const float* gstage0 =
      feats + ((size_t)(lane >> 4) * BATCH + b) * TAG + ((lane & 15) << 2);

  auto stage_chunk = [&](int base_s, int nb) {
    const float* g0 = gstage0 + (size_t)base_s * (BATCH * TAG);
#pragma unroll
    for (int q = 0; q < 16; ++q) {
      gld_lds16(g0 + (size_t)(4 * q) * (BATCH * TAG), &fchunk[nb][q * 256]);
    }
  };

  float p = (lane == START_IDX) ? 1.0f : 0.0f;
  int etot = 0;  // running power-of-2 count: M = etot * ln2 (exact scaling)

  // ---- prologue: stage chunk 0 and wait for it ----
  stage_chunk(0, 0);
  asm volatile("s_waitcnt vmcnt(0)" ::: "memory");
  __builtin_amdgcn_sched_barrier(0);
  __builtin_amdgcn_wave_barrier();

  // one step: 3 independent DS roots issued first; subtree A (pure VALU) hides
  // their latency; subtrees B/C/D + FMAs consume them afterwards.
  auto step = [&](float ex) {
    const unsigned pu = __float_as_uint(p);

    unsigned u[64];
    u[0]  = pu;
    u[16] = swz_x16(pu);                                             // DS
    u[32] = (unsigned)__builtin_amdgcn_ds_bpermute(addr32, (int)pu); // DS
    u[48] = (unsigned)__builtin_amdgcn_ds_bpermute(addr48, (int)pu); // DS

    // renorm (wave-uniform; overlaps the gather/FMA stream)
    const unsigned pb = __builtin_amdgcn_readlane(pu, 2);
    const unsigned eb = (pb == 0u) ? 127u : (pb >> 23);
    etot += (int)eb - 127;
    const float cg = ex * __uint_as_float((254u - eb) << 23);  // * 2^(127-eb)

    float aa[8];
#pragma unroll
    for (int k = 0; k < 8; ++k) aa[k] = 0.0f;

    // ---- subtree A: slots 0..15 (pure VALU, no DS dependence) ----
    subtree16(u);
#pragma unroll
    for (int k = 0; k < 16; ++k)
      aa[k & 7] = __builtin_fmaf(__uint_as_float(u[k]), Eg[k], aa[k & 7]);

    // ---- subtrees B/C/D: first use of the DS results (~190 cy after issue) ----
    subtree16(u + 16);
#pragma unroll
    for (int k = 16; k < 32; ++k)
      aa[k & 7] = __builtin_fmaf(__uint_as_float(u[k]), Eg[k], aa[k & 7]);
    subtree16(u + 32);
#pragma unroll
    for (int k = 32; k < 48; ++k)
      aa[k & 7] = __builtin_fmaf(__uint_as_float(u[k]), Eg[k], aa[k & 7]);
    subtree16(u + 48);
#pragma unroll
    for (int k = 48; k < 64; ++k)
      aa[k & 7] = __builtin_fmaf(__uint_as_float(u[k]), Eg[k], aa[k & 7]);

    const float t = ((aa[0] + aa[1]) + (aa[2] + aa[3])) +
                    ((aa[4] + aa[5]) + (aa[6] + aa[7]));
    p = t * cg;  // single on-chain multiply
  };

  for (int c = 0;; ++c) {
    const int base = c * CHUNK;
    int n = L - base;
    if (n <= 0) break;
    if (n > CHUNK) n = CHUNK;

    const int nbase = base + CHUNK;
    if (nbase < S_LEN) stage_chunk(nbase, (c + 1) & 1);  // async, 64 steps ahead

    const float* fb = &fchunk[c & 1][0];

    // 8-step groups: feat reads + exp batched off-chain
    auto group8 = [&](int s0) {
      float ex[8];
#pragma unroll
      for (int i = 0; i < 8; ++i) ex[i] = fb[(s0 + i) * TAG + lane];
#pragma unroll
      for (int i = 0; i < 8; ++i) ex[i] = __expf(ex[i]);
#pragma unroll
      for (int i = 0; i < 8; ++i) step(ex[i]);
    };

    if (n == CHUNK) {
      for (int g = 0; g < CHUNK / 8; ++g) group8(8 * g);
    } else {
      const int full = n >> 3;
      for (int g = 0; g < full; ++g) group8(8 * g);
      for (int i = full * 8; i < n; ++i) {  // tail (rare): on-chain exp is fine
        step(__expf(fb[i * TAG + lane]));
      }
      break;  // L reached inside this chunk
    }

    if (nbase >= L) break;  // done; skip the drain

    // next chunk's loads were issued 64 steps ago: drain is ~free
    asm volatile("s_waitcnt vmcnt(0)" ::: "memory");
    __builtin_amdgcn_sched_barrier(0);
    __builtin_amdgcn_wave_barrier();
  }

  // drain any in-flight staging before LDS is deallocated at wave exit
  asm volatile("s_waitcnt vmcnt(0)" ::: "memory");

  // ---- epilogue: out[b] = logsumexp_j(etot*ln2 + log p_j + trans[END, j]) ----
  {
    const float a = (float)etot * LN2F + __logf(p) + trans[END_IDX * TAG + lane];
    float mx = a;  // p==0 -> a=-inf; lane 2 always finite so mx finite
#pragma unroll
    for (int off = 32; off >= 1; off >>= 1) mx = fmaxf(mx, __shfl_xor(mx, off, 64));
    float e = __expf(a - mx);
#pragma unroll
    for (int off = 32; off >= 1; off >>= 1) e += __shfl_xor(e, off, 64);
    if (lane == 0) out[b] = mx + __logf(e);
  }
}

extern "C" void kernel_launch(void* const* d_in, const int* in_sizes, int n_in,
                              void* d_out, int out_size, void* d_ws, size_t ws_size,
                              hipStream_t stream) {
  const float* feats = (const float*)d_in[0];
  const float* mask = (const float*)d_in[1];
  const float* trans = (const float*)d_in[2];
  float* out = (float*)d_out;
  crf_fwd_kernel<<<dim3(BATCH), dim3(64), 0, stream>>>(feats, mask, trans, out);
}